// Round 12
// baseline (198.677 us; speedup 1.0000x reference)
//
#include <hip/hip_runtime.h>

#define EPSF 1e-8f

constexpr int D0 = 128;   // input dim
constexpr int R  = 256;   // random features
constexpr int D1 = 64;    // output dim
constexpr int BM = 128;   // rows per block
constexpr int NT = 512;   // threads per block (8 waves)
constexpr int TP = 68;    // transpose buffer stride (f32)

typedef __attribute__((ext_vector_type(8))) short  bf16x8;
typedef __attribute__((ext_vector_type(4))) float  f32x4;
typedef __attribute__((ext_vector_type(4))) uint   u32x4;

// ws layout (ushort elements): bf16 weights in MFMA fragment order
constexpr int WS_W1VAR = 32768;
constexpr int WS_W2MU  = 65536;
constexpr int WS_W2C   = 81920;
constexpr int WS_W2VAR = 98304;

__device__ __forceinline__ ushort f2bf(float x) {
    uint32_t u = __builtin_bit_cast(uint32_t, x);
    u += 0x7FFFu + ((u >> 16) & 1u);          // round-to-nearest-even
    return (ushort)(u >> 16);
}

__device__ __forceinline__ uint cvt_pk_bf16(float lo, float hi) {
    uint r;
    asm("v_cvt_pk_bf16_f32 %0, %1, %2" : "=v"(r) : "v"(lo), "v"(hi));
    return r;
}

// fast reciprocal (v_rcp_f32, ~1e-5 rel err; tolerance is ~2% of max)
__device__ __forceinline__ float fastrcp(float x) {
    return __builtin_amdgcn_rcpf(x);
}

// elementwise square of a bf16x8 fragment
__device__ __forceinline__ bf16x8 sq_bf16x8(bf16x8 a) {
    u32x4 u = __builtin_bit_cast(u32x4, a);
    u32x4 r;
    #pragma unroll
    for (int i = 0; i < 4; ++i) {
        float lo = __builtin_bit_cast(float, u[i] << 16);
        float hi = __builtin_bit_cast(float, u[i] & 0xFFFF0000u);
        r[i] = cvt_pk_bf16(lo * lo, hi * hi);
    }
    return __builtin_bit_cast(bf16x8, r);
}

// --- pre-kernel: convert weights to frag order + zero the output accums ----
__global__ void convert_w(const float* __restrict__ W1mu,
                          const float* __restrict__ W1var,
                          const float* __restrict__ W2mu,
                          const float* __restrict__ W2var,
                          ushort* __restrict__ ws,
                          float4* __restrict__ out4, int total4)
{
    int tid = blockIdx.x * 256 + threadIdx.x;
    if (tid < 8192) {                       // layer 1: 2 mats * 64 frags * 64 lanes
        int m    = tid >> 12;               // 0=mu 1=var
        int f    = (tid >> 6) & 63;         // frag = nt*4 + ks
        int lane = tid & 63;
        int nt = f >> 2, ks = f & 3;
        int col = nt * 16 + (lane & 15);    // rf index (W1 row)
        int k0  = ks * 32 + (lane >> 4) * 8;
        const float* src = (m ? W1var : W1mu) + (size_t)col * D0 + k0;
        ushort* dst = ws + (m ? WS_W1VAR : 0) + (size_t)(f * 64 + lane) * 8;
        #pragma unroll
        for (int j = 0; j < 8; ++j) dst[j] = f2bf(src[j]);
    } else if (tid < 8192 + 3 * 2048) {     // layer 2: 3 mats * 32 frags * 64 lanes
        int t2   = tid - 8192;
        int m    = t2 >> 11;                // 0=mu 1=c 2=var
        int f    = (t2 >> 6) & 31;          // frag = nt*8 + ks
        int lane = t2 & 63;
        int nt = f >> 3, ks = f & 7;
        int col = nt * 16 + (lane & 15);    // d1 index (W2 row)
        int k0  = ks * 32 + (lane >> 4) * 8;
        const float* smu = W2mu  + (size_t)col * R + k0;
        const float* svr = W2var + (size_t)col * R + k0;
        ushort* dst = ws + WS_W2MU + m * 16384 + (size_t)(f * 64 + lane) * 8;
        #pragma unroll
        for (int j = 0; j < 8; ++j) {
            float v;
            if (m == 0)      v = smu[j];
            else if (m == 1) v = fmaf(smu[j], smu[j], svr[j]);  // var + mu^2
            else             v = svr[j];
            dst[j] = f2bf(v);
        }
    }
    // zero the output accumulators (replaces hipMemsetAsync; harness does not
    // re-poison between replays, so this must run every call)
    float4 z = {0.f, 0.f, 0.f, 0.f};
    int nth = gridDim.x * 256;
    for (int i = tid; i < total4; i += nth) out4[i] = z;
}

// --- fused main kernel ------------------------------------------------------
// BM=128, 8 waves, 128 KB LDS (1 block/CU, 2 waves/SIMD).
// Halves weight L2 traffic vs BM=64 (the proven binder, r10): 2048 blocks x
// 224 KB = 459 MB. Weights reg-cached across 8 row-tiles per wave.
__global__ __launch_bounds__(NT, 2)
void dgp_mfma(const float* __restrict__ X,
              const int*   __restrict__ Xidx,
              const ushort* __restrict__ ws,
              float* __restrict__ accM,
              float* __restrict__ accP)
{
    // 128 KB, phase-aliased:
    //  A: ushort XB[128][128], XQ[128][128] (32+32 KB, first half of sh)
    //  B: ushort M1s/V1s[128][256]          (64+64 KB)
    //  C: float  Vp/Mp[128][68]             (34.8+34.8 KB)
    __shared__ __align__(16) ushort sh[2 * BM * R];
    ushort* M1s = sh;
    ushort* V1s = sh + BM * R;

    const int t    = threadIdx.x;
    const int lane = t & 63;
    const int w    = t >> 6;         // wave 0..7
    const int row0 = blockIdx.x * BM;
    const int lcol = lane & 15;      // X-row within 16-tile
    const int lk   = lane >> 4;      // 0..3

    // ---------------- Stage X as converted bf16 slabs (once) ----------------
    {
        ushort* XB = sh;             // [128][128] bf16, granule-XOR swizzle
        ushort* XQ = sh + BM * 128;
        int row = t >> 2;            // 0..127
        int q   = t & 3;             // 32-float quarter
        const float4* src = (const float4*)(X + (size_t)(row0 + row) * D0) + q * 8;
        #pragma unroll
        for (int p = 0; p < 4; ++p) {       // granule-pair p: floats [p*8, p*8+8)
            float4 a = src[p * 2], b = src[p * 2 + 1];
            u32x4 bb, qq;
            bb[0] = cvt_pk_bf16(a.x, a.y); bb[1] = cvt_pk_bf16(a.z, a.w);
            bb[2] = cvt_pk_bf16(b.x, b.y); bb[3] = cvt_pk_bf16(b.z, b.w);
            qq[0] = cvt_pk_bf16(a.x * a.x, a.y * a.y);
            qq[1] = cvt_pk_bf16(a.z * a.z, a.w * a.w);
            qq[2] = cvt_pk_bf16(b.x * b.x, b.y * b.y);
            qq[3] = cvt_pk_bf16(b.z * b.z, b.w * b.w);
            int gs = (q * 4 + p) ^ (row & 7);
            *(u32x4*)&XB[row * 128 + gs * 8] = bb;
            *(u32x4*)&XQ[row * 128 + gs * 8] = qq;
        }
    }
    __syncthreads();

    // ---------------- Layer 1: W1·X^T (mu) and W1var·(X^2)^T ----------------
    // wave w owns rf-tiles {2w, 2w+1}, all 8 row-tiles
    const ushort* XB = sh;
    const ushort* XQ = sh + BM * 128;
    f32x4 accm[2][8], accv[2][8];   // [ntl][rt] — 128 VGPRs
    #pragma unroll
    for (int ntl = 0; ntl < 2; ++ntl)
        #pragma unroll
        for (int rt = 0; rt < 8; ++rt) {
            accm[ntl][rt] = (f32x4)0.f;
            accv[ntl][rt] = (f32x4)0.f;
        }

    #pragma unroll
    for (int ks = 0; ks < 4; ++ks) {
        bf16x8 amu[2], avr[2];
        #pragma unroll
        for (int ntl = 0; ntl < 2; ++ntl) {
            int f = (w * 2 + ntl) * 4 + ks;
            amu[ntl] = *(const bf16x8*)(ws + (size_t)(f * 64 + lane) * 8);
            avr[ntl] = *(const bf16x8*)(ws + WS_W1VAR + (size_t)(f * 64 + lane) * 8);
        }
        #pragma unroll
        for (int rt = 0; rt < 8; ++rt) {
            int xrow = rt * 16 + lcol;
            int gidx = (ks * 4 + lk) ^ (xrow & 7);
            bf16x8 xb = *(const bf16x8*)&XB[xrow * 128 + gidx * 8];
            bf16x8 xq = *(const bf16x8*)&XQ[xrow * 128 + gidx * 8];
            #pragma unroll
            for (int ntl = 0; ntl < 2; ++ntl) {
                accm[ntl][rt] = __builtin_amdgcn_mfma_f32_16x16x32_bf16(amu[ntl], xb, accm[ntl][rt], 0, 0, 0);
                accv[ntl][rt] = __builtin_amdgcn_mfma_f32_16x16x32_bf16(avr[ntl], xq, accv[ntl][rt], 0, 0, 0);
            }
        }
    }

    __syncthreads();   // all XB/XQ reads done before slabs overwrite region

    // RF-ReLU epilogue -> b64 LDS writes (XOR-swizzled, 16B granule)
    const float SCALE  = 0.08838834764831845f;  // sqrt(2/256)
    const float SCALE2 = 0.0078125f;            // 2/256
    #pragma unroll
    for (int ntl = 0; ntl < 2; ++ntl) {
        int rf0 = (w * 2 + ntl) * 16 + lk * 4;
        #pragma unroll
        for (int rt = 0; rt < 8; ++rt) {
            int xrow = rt * 16 + lcol;
            float m1[4], v1[4];
            #pragma unroll
            for (int i = 0; i < 4; ++i) {
                float om = accm[ntl][rt][i];
                float ov = accv[ntl][rt][i];
                bool pos = om > 0.f;
                m1[i] = pos ? SCALE  * om : 0.f;
                v1[i] = pos ? SCALE2 * ov : 0.f;
            }
            uint2 pm, pv;
            pm.x = cvt_pk_bf16(m1[0], m1[1]); pm.y = cvt_pk_bf16(m1[2], m1[3]);
            pv.x = cvt_pk_bf16(v1[0], v1[1]); pv.y = cvt_pk_bf16(v1[2], v1[3]);
            int idx = xrow * 256 + (rf0 ^ ((xrow & 7) << 3));
            *(uint2*)&M1s[idx] = pm;
            *(uint2*)&V1s[idx] = pv;
        }
    }

    __syncthreads();

    // ---------------- Layer 2: wave = (d1-tile, ks-half) --------------------
    const int d = w & 3;        // d1-tile (16 cols)
    const int h = w >> 2;       // ks-half: ks in [h*4, h*4+4)
    f32x4 m2a[8], v2a[8];       // [rt] partial sums over this ks-half
    #pragma unroll
    for (int rt = 0; rt < 8; ++rt) { m2a[rt] = (f32x4)0.f; v2a[rt] = (f32x4)0.f; }

    #pragma unroll
    for (int kk = 0; kk < 4; ++kk) {
        int ks = h * 4 + kk;
        int f  = d * 8 + ks;
        bf16x8 amu = *(const bf16x8*)(ws + WS_W2MU  + (size_t)(f * 64 + lane) * 8);
        bf16x8 ac  = *(const bf16x8*)(ws + WS_W2C   + (size_t)(f * 64 + lane) * 8);
        bf16x8 avr = *(const bf16x8*)(ws + WS_W2VAR + (size_t)(f * 64 + lane) * 8);
        #pragma unroll
        for (int rt = 0; rt < 8; ++rt) {
            int xrow = rt * 16 + lcol;
            int base = xrow * 256 + ((ks * 32 + lk * 8) ^ ((xrow & 7) << 3));
            bf16x8 bm  = *(const bf16x8*)&M1s[base];
            bf16x8 bv  = *(const bf16x8*)&V1s[base];
            bf16x8 bms = sq_bf16x8(bm);
            m2a[rt] = __builtin_amdgcn_mfma_f32_16x16x32_bf16(amu, bm,  m2a[rt], 0, 0, 0);
            v2a[rt] = __builtin_amdgcn_mfma_f32_16x16x32_bf16(ac,  bv,  v2a[rt], 0, 0, 0);
            v2a[rt] = __builtin_amdgcn_mfma_f32_16x16x32_bf16(avr, bms, v2a[rt], 0, 0, 0);
        }
    }

    __syncthreads();   // all slab reads done before transpose reuses region

    // ---------------- Combine ks-half partials via transpose buffer ---------
    float* Vp = (float*)sh;            // [128][TP] raw v2
    float* Mp = Vp + BM * TP;          // [128][TP] raw m2
    if (h == 0) {
        #pragma unroll
        for (int rt = 0; rt < 8; ++rt) {
            int xrow = rt * 16 + lcol;
            int d1   = d * 16 + lk * 4;
            *(f32x4*)&Vp[xrow * TP + d1] = v2a[rt];
            *(f32x4*)&Mp[xrow * TP + d1] = m2a[rt];
        }
    }
    __syncthreads();
    if (h == 1) {
        #pragma unroll
        for (int rt = 0; rt < 8; ++rt) {
            int xrow = rt * 16 + lcol;
            int d1   = d * 16 + lk * 4;
            f32x4 vv = *(const f32x4*)&Vp[xrow * TP + d1];
            f32x4 mm = *(const f32x4*)&Mp[xrow * TP + d1];
            vv += v2a[rt];
            mm += m2a[rt];
            *(f32x4*)&Vp[xrow * TP + d1] = vv;
            *(f32x4*)&Mp[xrow * TP + d1] = mm;
        }
    }
    __syncthreads();

    // ---------------- Row-coalesced atomic scatter --------------------------
    // 8 waves x 16 rows; per instruction: one uniform row, 64 consecutive floats
    #pragma unroll
    for (int r = 0; r < 16; ++r) {
        int row = w * 16 + r;
        int g   = __builtin_amdgcn_readfirstlane(Xidx[row0 + row]);
        float vv = Vp[row * TP + lane];
        float mm = Mp[row * TP + lane];
        float p  = fastrcp(vv + EPSF);
        atomicAdd(accP + (size_t)g * D1 + lane, p);
        atomicAdd(accM + (size_t)g * D1 + lane, p * mm);
    }
}

__global__ void dgp_finalize(float4* __restrict__ accM4,
                             float4* __restrict__ accP4, int total4)
{
    int idx = blockIdx.x * blockDim.x + threadIdx.x;
    if (idx < total4) {
        float4 pv = accP4[idx];
        float4 var;
        var.x = fastrcp(pv.x + EPSF);
        var.y = fastrcp(pv.y + EPSF);
        var.z = fastrcp(pv.z + EPSF);
        var.w = fastrcp(pv.w + EPSF);
        accP4[idx] = var;                        // embedd_vars
        float4 mv = accM4[idx];
        mv.x *= var.x; mv.y *= var.y; mv.z *= var.z; mv.w *= var.w;
        accM4[idx] = mv;                         // embedd_means
    }
}

extern "C" void kernel_launch(void* const* d_in, const int* in_sizes, int n_in,
                              void* d_out, int out_size, void* d_ws, size_t ws_size,
                              hipStream_t stream)
{
    const float* X     = (const float*)d_in[0];
    const int*   Xidx  = (const int*)d_in[1];
    const float* W1mu  = (const float*)d_in[2];
    const float* W1var = (const float*)d_in[3];
    const float* W2mu  = (const float*)d_in[4];
    const float* W2var = (const float*)d_in[5];

    const int N = in_sizes[0] / D0;            // 262144
    const int U = out_size / (2 * D1);         // 50000
    float* out  = (float*)d_out;
    float* accM = out;                          // means region
    float* accP = out + (size_t)U * D1;         // vars region
    ushort* ws  = (ushort*)d_ws;
    const int total4 = out_size / 4;           // float4 count

    // convert weights AND zero the accumulators (memset folded in)
    convert_w<<<2048, 256, 0, stream>>>(W1mu, W1var, W2mu, W2var, ws,
                                        (float4*)d_out, total4);

    dgp_mfma<<<N / BM, NT, 0, stream>>>(X, Xidx, ws, accM, accP);

    const int fin4 = (U * D1) / 4;             // per-array float4 count
    dgp_finalize<<<(fin4 + 255) / 256, 256, 0, stream>>>(
        (float4*)accM, (float4*)accP, fin4);
}

// Round 13
// 154.772 us; speedup vs baseline: 1.2837x; 1.2837x over previous
//
#include <hip/hip_runtime.h>

#define EPSF 1e-8f

constexpr int D0 = 128;   // input dim
constexpr int R  = 256;   // random features
constexpr int D1 = 64;    // output dim
constexpr int BM = 64;    // rows per block
constexpr int NT = 512;   // threads per block (8 waves)
constexpr int TP = 68;    // transpose buffer stride (f32)

typedef __attribute__((ext_vector_type(8))) short  bf16x8;
typedef __attribute__((ext_vector_type(4))) float  f32x4;
typedef __attribute__((ext_vector_type(4))) uint   u32x4;

// ws layout: [0, 229376) bf16 weight frags (ushort offsets below),
// then (512-aligned) float acc[U][128]: cols 0-63 = P-sum, 64-127 = M-sum.
constexpr int WS_W1VAR = 32768;
constexpr int WS_W2MU  = 65536;
constexpr int WS_W2C   = 81920;
constexpr int WS_W2VAR = 98304;
constexpr size_t WS_WEIGHT_BYTES = 229376;

__device__ __forceinline__ ushort f2bf(float x) {
    uint32_t u = __builtin_bit_cast(uint32_t, x);
    u += 0x7FFFu + ((u >> 16) & 1u);          // round-to-nearest-even
    return (ushort)(u >> 16);
}

__device__ __forceinline__ uint cvt_pk_bf16(float lo, float hi) {
    uint r;
    asm("v_cvt_pk_bf16_f32 %0, %1, %2" : "=v"(r) : "v"(lo), "v"(hi));
    return r;
}

// fast reciprocal (v_rcp_f32, ~1e-5 rel err; tolerance is ~2% of max)
__device__ __forceinline__ float fastrcp(float x) {
    return __builtin_amdgcn_rcpf(x);
}

// elementwise square of a bf16x8 fragment
__device__ __forceinline__ bf16x8 sq_bf16x8(bf16x8 a) {
    u32x4 u = __builtin_bit_cast(u32x4, a);
    u32x4 r;
    #pragma unroll
    for (int i = 0; i < 4; ++i) {
        float lo = __builtin_bit_cast(float, u[i] << 16);
        float hi = __builtin_bit_cast(float, u[i] & 0xFFFF0000u);
        r[i] = cvt_pk_bf16(lo * lo, hi * hi);
    }
    return __builtin_bit_cast(bf16x8, r);
}

// --- pre-kernel: convert weights to frag order + zero the ws accumulator ---
__global__ void convert_w(const float* __restrict__ W1mu,
                          const float* __restrict__ W1var,
                          const float* __restrict__ W2mu,
                          const float* __restrict__ W2var,
                          ushort* __restrict__ ws,
                          float4* __restrict__ acc4, int total4)
{
    int tid = blockIdx.x * 256 + threadIdx.x;
    if (tid < 8192) {                       // layer 1: 2 mats * 64 frags * 64 lanes
        int m    = tid >> 12;               // 0=mu 1=var
        int f    = (tid >> 6) & 63;         // frag = nt*4 + ks
        int lane = tid & 63;
        int nt = f >> 2, ks = f & 3;
        int col = nt * 16 + (lane & 15);    // rf index (W1 row)
        int k0  = ks * 32 + (lane >> 4) * 8;
        const float* src = (m ? W1var : W1mu) + (size_t)col * D0 + k0;
        ushort* dst = ws + (m ? WS_W1VAR : 0) + (size_t)(f * 64 + lane) * 8;
        #pragma unroll
        for (int j = 0; j < 8; ++j) dst[j] = f2bf(src[j]);
    } else if (tid < 8192 + 3 * 2048) {     // layer 2: 3 mats * 32 frags * 64 lanes
        int t2   = tid - 8192;
        int m    = t2 >> 11;                // 0=mu 1=c 2=var
        int f    = (t2 >> 6) & 31;          // frag = nt*8 + ks
        int lane = t2 & 63;
        int nt = f >> 3, ks = f & 7;
        int col = nt * 16 + (lane & 15);    // d1 index (W2 row)
        int k0  = ks * 32 + (lane >> 4) * 8;
        const float* smu = W2mu  + (size_t)col * R + k0;
        const float* svr = W2var + (size_t)col * R + k0;
        ushort* dst = ws + WS_W2MU + m * 16384 + (size_t)(f * 64 + lane) * 8;
        #pragma unroll
        for (int j = 0; j < 8; ++j) {
            float v;
            if (m == 0)      v = smu[j];
            else if (m == 1) v = fmaf(smu[j], smu[j], svr[j]);  // var + mu^2
            else             v = svr[j];
            dst[j] = f2bf(v);
        }
    }
    // zero the ws accumulator (harness does not re-poison between replays)
    float4 z = {0.f, 0.f, 0.f, 0.f};
    int nth = gridDim.x * 256;
    for (int i = tid; i < total4; i += nth) acc4[i] = z;
}

// --- fused main kernel (r11 structure, verified 159us) -----------------------
// BM=64, 8 waves, 64 KB LDS (2 blocks/CU).
//  - X staged once as pre-converted bf16 slabs XB/XQ (granule-XOR swizzle)
//  - layer 1: wave owns 2 rf-tiles x all 4 row-tiles (disjoint weight frags)
//  - layer 2: wave = (d1-tile, ks-half) (disjoint weight frags); partials
//    combined through the LDS transpose buffer
//  - scatter: one wave-uniform row per atomic instruction; P and M interleaved
//    in ws ([key][128]) so each row's atomics hit one 512B region
__global__ __launch_bounds__(NT, 4)
void dgp_mfma(const float* __restrict__ X,
              const int*   __restrict__ Xidx,
              const ushort* __restrict__ ws,
              float* __restrict__ acc)
{
    __shared__ __align__(16) ushort sh[2 * BM * R];
    ushort* M1s = sh;
    ushort* V1s = sh + BM * R;

    const int t    = threadIdx.x;
    const int lane = t & 63;
    const int w    = t >> 6;         // wave 0..7
    const int row0 = blockIdx.x * BM;
    const int lcol = lane & 15;      // X-row within 16-tile
    const int lk   = lane >> 4;      // 0..3

    // ---------------- Stage X as converted bf16 slabs (once) ----------------
    {
        ushort* XB = sh;             // [64][128] bf16, granule-XOR swizzle
        ushort* XQ = sh + 8192;
        int row = t >> 3;            // 0..63
        int cb  = t & 7;             // 16-float chunk = 2 granules
        const float4* src = (const float4*)(X + (size_t)(row0 + row) * D0) + cb * 4;
        float4 a0 = src[0], a1 = src[1], a2 = src[2], a3 = src[3];
        u32x4 b0, b1, q0, q1;
        b0[0] = cvt_pk_bf16(a0.x, a0.y); b0[1] = cvt_pk_bf16(a0.z, a0.w);
        b0[2] = cvt_pk_bf16(a1.x, a1.y); b0[3] = cvt_pk_bf16(a1.z, a1.w);
        b1[0] = cvt_pk_bf16(a2.x, a2.y); b1[1] = cvt_pk_bf16(a2.z, a2.w);
        b1[2] = cvt_pk_bf16(a3.x, a3.y); b1[3] = cvt_pk_bf16(a3.z, a3.w);
        q0[0] = cvt_pk_bf16(a0.x * a0.x, a0.y * a0.y);
        q0[1] = cvt_pk_bf16(a0.z * a0.z, a0.w * a0.w);
        q0[2] = cvt_pk_bf16(a1.x * a1.x, a1.y * a1.y);
        q0[3] = cvt_pk_bf16(a1.z * a1.z, a1.w * a1.w);
        q1[0] = cvt_pk_bf16(a2.x * a2.x, a2.y * a2.y);
        q1[1] = cvt_pk_bf16(a2.z * a2.z, a2.w * a2.w);
        q1[2] = cvt_pk_bf16(a3.x * a3.x, a3.y * a3.y);
        q1[3] = cvt_pk_bf16(a3.z * a3.z, a3.w * a3.w);
        int gs0 = (cb * 2) ^ (row & 7);
        int gs1 = (cb * 2 + 1) ^ (row & 7);
        *(u32x4*)&XB[row * 128 + gs0 * 8] = b0;
        *(u32x4*)&XB[row * 128 + gs1 * 8] = b1;
        *(u32x4*)&XQ[row * 128 + gs0 * 8] = q0;
        *(u32x4*)&XQ[row * 128 + gs1 * 8] = q1;
    }
    __syncthreads();

    // ---------------- Layer 1: W1·X^T (mu) and W1var·(X^2)^T ----------------
    // wave w owns rf-tiles {2w, 2w+1}, all 4 row-tiles
    const ushort* XB = sh;
    const ushort* XQ = sh + 8192;
    f32x4 accm[2][4], accv[2][4];   // [ntl][rt]
    #pragma unroll
    for (int ntl = 0; ntl < 2; ++ntl)
        #pragma unroll
        for (int rt = 0; rt < 4; ++rt) {
            accm[ntl][rt] = (f32x4)0.f;
            accv[ntl][rt] = (f32x4)0.f;
        }

    #pragma unroll
    for (int ks = 0; ks < 4; ++ks) {
        bf16x8 amu[2], avr[2];
        #pragma unroll
        for (int ntl = 0; ntl < 2; ++ntl) {
            int f = (w * 2 + ntl) * 4 + ks;
            amu[ntl] = *(const bf16x8*)(ws + (size_t)(f * 64 + lane) * 8);
            avr[ntl] = *(const bf16x8*)(ws + WS_W1VAR + (size_t)(f * 64 + lane) * 8);
        }
        #pragma unroll
        for (int rt = 0; rt < 4; ++rt) {
            int xrow = rt * 16 + lcol;
            int gidx = (ks * 4 + lk) ^ (xrow & 7);
            bf16x8 xb = *(const bf16x8*)&XB[xrow * 128 + gidx * 8];
            bf16x8 xq = *(const bf16x8*)&XQ[xrow * 128 + gidx * 8];
            #pragma unroll
            for (int ntl = 0; ntl < 2; ++ntl) {
                accm[ntl][rt] = __builtin_amdgcn_mfma_f32_16x16x32_bf16(amu[ntl], xb, accm[ntl][rt], 0, 0, 0);
                accv[ntl][rt] = __builtin_amdgcn_mfma_f32_16x16x32_bf16(avr[ntl], xq, accv[ntl][rt], 0, 0, 0);
            }
        }
    }

    __syncthreads();   // all XB/XQ reads done before slabs overwrite region

    // RF-ReLU epilogue -> b64 LDS writes (XOR-swizzled, 16B granule)
    const float SCALE  = 0.08838834764831845f;  // sqrt(2/256)
    const float SCALE2 = 0.0078125f;            // 2/256
    #pragma unroll
    for (int ntl = 0; ntl < 2; ++ntl) {
        int rf0 = (w * 2 + ntl) * 16 + lk * 4;
        #pragma unroll
        for (int rt = 0; rt < 4; ++rt) {
            int xrow = rt * 16 + lcol;
            float m1[4], v1[4];
            #pragma unroll
            for (int i = 0; i < 4; ++i) {
                float om = accm[ntl][rt][i];
                float ov = accv[ntl][rt][i];
                bool pos = om > 0.f;
                m1[i] = pos ? SCALE  * om : 0.f;
                v1[i] = pos ? SCALE2 * ov : 0.f;
            }
            uint2 pm, pv;
            pm.x = cvt_pk_bf16(m1[0], m1[1]); pm.y = cvt_pk_bf16(m1[2], m1[3]);
            pv.x = cvt_pk_bf16(v1[0], v1[1]); pv.y = cvt_pk_bf16(v1[2], v1[3]);
            int idx = xrow * 256 + (rf0 ^ ((xrow & 7) << 3));
            *(uint2*)&M1s[idx] = pm;
            *(uint2*)&V1s[idx] = pv;
        }
    }

    __syncthreads();

    // ---------------- Layer 2: wave = (d1-tile, ks-half) --------------------
    const int d = w & 3;        // d1-tile (16 cols)
    const int h = w >> 2;       // ks-half: ks in [h*4, h*4+4)
    f32x4 m2a[4], v2a[4];       // [rt] partial sums over this ks-half
    #pragma unroll
    for (int rt = 0; rt < 4; ++rt) { m2a[rt] = (f32x4)0.f; v2a[rt] = (f32x4)0.f; }

    #pragma unroll
    for (int kk = 0; kk < 4; ++kk) {
        int ks = h * 4 + kk;
        int f  = d * 8 + ks;
        bf16x8 amu = *(const bf16x8*)(ws + WS_W2MU  + (size_t)(f * 64 + lane) * 8);
        bf16x8 ac  = *(const bf16x8*)(ws + WS_W2C   + (size_t)(f * 64 + lane) * 8);
        bf16x8 avr = *(const bf16x8*)(ws + WS_W2VAR + (size_t)(f * 64 + lane) * 8);
        #pragma unroll
        for (int rt = 0; rt < 4; ++rt) {
            int xrow = rt * 16 + lcol;
            int base = xrow * 256 + ((ks * 32 + lk * 8) ^ ((xrow & 7) << 3));
            bf16x8 bm  = *(const bf16x8*)&M1s[base];
            bf16x8 bv  = *(const bf16x8*)&V1s[base];
            bf16x8 bms = sq_bf16x8(bm);
            m2a[rt] = __builtin_amdgcn_mfma_f32_16x16x32_bf16(amu, bm,  m2a[rt], 0, 0, 0);
            v2a[rt] = __builtin_amdgcn_mfma_f32_16x16x32_bf16(ac,  bv,  v2a[rt], 0, 0, 0);
            v2a[rt] = __builtin_amdgcn_mfma_f32_16x16x32_bf16(avr, bms, v2a[rt], 0, 0, 0);
        }
    }

    __syncthreads();   // all slab reads done before transpose reuses region

    // ---------------- Combine ks-half partials via transpose buffer ---------
    float* Vp = (float*)sh;            // [64][TP] raw v2
    float* Mp = Vp + BM * TP;          // [64][TP] raw m2
    if (h == 0) {
        #pragma unroll
        for (int rt = 0; rt < 4; ++rt) {
            int xrow = rt * 16 + lcol;
            int d1   = d * 16 + lk * 4;
            *(f32x4*)&Vp[xrow * TP + d1] = v2a[rt];
            *(f32x4*)&Mp[xrow * TP + d1] = m2a[rt];
        }
    }
    __syncthreads();
    if (h == 1) {
        #pragma unroll
        for (int rt = 0; rt < 4; ++rt) {
            int xrow = rt * 16 + lcol;
            int d1   = d * 16 + lk * 4;
            f32x4 vv = *(const f32x4*)&Vp[xrow * TP + d1];
            f32x4 mm = *(const f32x4*)&Mp[xrow * TP + d1];
            vv += v2a[rt];
            mm += m2a[rt];
            *(f32x4*)&Vp[xrow * TP + d1] = vv;
            *(f32x4*)&Mp[xrow * TP + d1] = mm;
        }
    }
    __syncthreads();

    // ---------------- Row-coalesced atomic scatter (interleaved acc) --------
    // 8 waves x 8 rows; per row: two atomic instructions into ONE contiguous
    // 512B region acc[g][0..127] (P cols 0-63, M cols 64-127)
    #pragma unroll
    for (int r = 0; r < 8; ++r) {
        int row = w * 8 + r;
        int g   = __builtin_amdgcn_readfirstlane(Xidx[row0 + row]);
        float vv = Vp[row * TP + lane];
        float mm = Mp[row * TP + lane];
        float p  = fastrcp(vv + EPSF);
        float* base = acc + (size_t)g * 128;
        atomicAdd(base + lane, p);
        atomicAdd(base + 64 + lane, p * mm);
    }
}

// --- finalize: de-interleave acc -> (means, vars), writes ALL of d_out ------
__global__ void dgp_finalize(const float4* __restrict__ acc4,
                             float4* __restrict__ outM4,
                             float4* __restrict__ outV4, int total)
{
    int idx = blockIdx.x * blockDim.x + threadIdx.x;   // one per (key, d1/4)
    if (idx < total) {
        int g  = idx >> 4;
        int d4 = idx & 15;
        float4 P = acc4[(size_t)g * 32 + d4];
        float4 M = acc4[(size_t)g * 32 + 16 + d4];
        float4 var, mean;
        var.x = fastrcp(P.x + EPSF); var.y = fastrcp(P.y + EPSF);
        var.z = fastrcp(P.z + EPSF); var.w = fastrcp(P.w + EPSF);
        mean.x = M.x * var.x; mean.y = M.y * var.y;
        mean.z = M.z * var.z; mean.w = M.w * var.w;
        outM4[idx] = mean;                 // embedd_means
        outV4[idx] = var;                  // embedd_vars
    }
}

extern "C" void kernel_launch(void* const* d_in, const int* in_sizes, int n_in,
                              void* d_out, int out_size, void* d_ws, size_t ws_size,
                              hipStream_t stream)
{
    const float* X     = (const float*)d_in[0];
    const int*   Xidx  = (const int*)d_in[1];
    const float* W1mu  = (const float*)d_in[2];
    const float* W1var = (const float*)d_in[3];
    const float* W2mu  = (const float*)d_in[4];
    const float* W2var = (const float*)d_in[5];

    const int N = in_sizes[0] / D0;            // 262144
    const int U = out_size / (2 * D1);         // 50000
    float* out  = (float*)d_out;
    ushort* ws  = (ushort*)d_ws;
    float* acc  = (float*)((char*)d_ws + WS_WEIGHT_BYTES);  // [U][128] f32

    // convert weights AND zero the ws accumulator (one launch)
    const int accTotal4 = U * 32;              // U*128 floats as float4
    convert_w<<<2048, 256, 0, stream>>>(W1mu, W1var, W2mu, W2var, ws,
                                        (float4*)acc, accTotal4);

    dgp_mfma<<<N / BM, NT, 0, stream>>>(X, Xidx, ws, acc);

    const int finTotal = U * 16;               // one thread per (key, 4 d1)
    dgp_finalize<<<(finTotal + 255) / 256, 256, 0, stream>>>(
        (const float4*)acc, (float4*)out, (float4*)(out + (size_t)U * D1),
        finTotal);
}